// Round 3
// baseline (873.052 us; speedup 1.0000x reference)
//
#include <hip/hip_runtime.h>
#include <math.h>

#define F_IN 512
#define HDIM 16
#define CDIM 7

// ------------------------------------------------------------------- zero ----
__global__ __launch_bounds__(256) void k_zero(unsigned* __restrict__ deg, int n) {
    int i = blockIdx.x * 256 + threadIdx.x;
    if (i < n) deg[i] = 0u;
}

// -------------------------------------------------------------- histogram ----
__global__ __launch_bounds__(256) void k_hist(const int* __restrict__ dst,
                                              unsigned* __restrict__ deg, int E) {
    int e = blockIdx.x * 256 + threadIdx.x;
    if (e < E) atomicAdd(&deg[dst[e]], 1u);
}

// -------------------------------------------- scan stage 1: per-block scan ----
__global__ __launch_bounds__(256) void k_scan_block(const unsigned* __restrict__ deg,
                                                    unsigned* __restrict__ ptr,
                                                    unsigned* __restrict__ bsum, int n) {
    __shared__ unsigned s[256];
    int i = blockIdx.x * 256 + threadIdx.x;
    unsigned v = (i < n) ? deg[i] : 0u;
    s[threadIdx.x] = v;
    __syncthreads();
    for (int off = 1; off < 256; off <<= 1) {
        unsigned t = (threadIdx.x >= off) ? s[threadIdx.x - off] : 0u;
        __syncthreads();
        s[threadIdx.x] += t;
        __syncthreads();
    }
    if (i < n) ptr[i] = s[threadIdx.x] - v;          // exclusive within block
    if (threadIdx.x == 255) bsum[blockIdx.x] = s[255];
}

// ---------------------------------------- scan stage 2: scan block totals ----
__global__ __launch_bounds__(512) void k_scan_sums(unsigned* __restrict__ bsum, int nb) {
    __shared__ unsigned s[512];
    int t = threadIdx.x;
    unsigned v = (t < nb) ? bsum[t] : 0u;
    s[t] = v;
    __syncthreads();
    for (int off = 1; off < 512; off <<= 1) {
        unsigned u = (t >= off) ? s[t - off] : 0u;
        __syncthreads();
        s[t] += u;
        __syncthreads();
    }
    if (t < nb) bsum[t] = s[t] - v;                  // exclusive block offsets
}

// ------------------------- scan stage 3: add offsets, init fill and dinv ----
__global__ __launch_bounds__(256) void k_scan_add(unsigned* __restrict__ ptr,
                                                  unsigned* __restrict__ fill,
                                                  const unsigned* __restrict__ bsum,
                                                  const unsigned* __restrict__ deg,
                                                  float* __restrict__ dinv, int n) {
    int i = blockIdx.x * 256 + threadIdx.x;
    if (i >= n) return;
    unsigned p = ptr[i] + bsum[i >> 8];
    ptr[i] = p;
    fill[i] = p;
    dinv[i] = rsqrtf((float)deg[i] + 1.0f);          // +1 self-loop
}

// --------------------------------------------- CSR fill (counting sort) ----
__global__ __launch_bounds__(256) void k_csr(const int* __restrict__ src,
                                             const int* __restrict__ dst,
                                             unsigned* __restrict__ fill,
                                             unsigned* __restrict__ csr, int E) {
    int e = blockIdx.x * 256 + threadIdx.x;
    if (e >= E) return;
    unsigned slot = atomicAdd(&fill[dst[e]], 1u);
    csr[slot] = (unsigned)src[e];
}

// ------------------------------------------------------------------ GEMM1 ----
// g1[row][k] = (x[row] @ W1)[k] * dinv[row]
__global__ __launch_bounds__(256) void k_gemm1(const float* __restrict__ x,
                                               const float* __restrict__ W,
                                               const float* __restrict__ dinv,
                                               float* __restrict__ g1, int n) {
    int row = blockIdx.x * 256 + threadIdx.x;
    if (row >= n) return;
    const float4* __restrict__ x4 = (const float4*)(x + (size_t)row * F_IN);
    float acc[HDIM];
#pragma unroll
    for (int k = 0; k < HDIM; ++k) acc[k] = 0.f;
#pragma unroll 2
    for (int f4 = 0; f4 < F_IN / 4; ++f4) {
        float4 xv = x4[f4];
#pragma unroll
        for (int j = 0; j < 4; ++j) {
            float xs = (&xv.x)[j];
            const float* wrow = W + (size_t)(f4 * 4 + j) * HDIM;  // wave-uniform -> scalar
#pragma unroll
            for (int k = 0; k < HDIM; ++k) acc[k] += xs * wrow[k];
        }
    }
    float di = dinv[row];
    float4* g1o = (float4*)(g1 + (size_t)row * HDIM);
#pragma unroll
    for (int k4 = 0; k4 < 4; ++k4) {
        float4 g;
        g.x = acc[k4 * 4 + 0] * di;
        g.y = acc[k4 * 4 + 1] * di;
        g.z = acc[k4 * 4 + 2] * di;
        g.w = acc[k4 * 4 + 3] * di;
        g1o[k4] = g;
    }
}

// -------------------------------------------------- gather 1 (wave/node) ----
// agg1[d][k] = dinv[d] * ( g1[d][k] + sum_{s in in(d)} g1[s][k] )
__global__ __launch_bounds__(256) void k_gather1(const unsigned* __restrict__ ptr,
                                                 const unsigned* __restrict__ deg,
                                                 const unsigned* __restrict__ csr,
                                                 const float* __restrict__ g1,
                                                 const float* __restrict__ dinv,
                                                 float* __restrict__ agg1, int n) {
    int node = blockIdx.x * 4 + (threadIdx.x >> 6);   // wave-uniform
    if (node >= n) return;
    int lane = threadIdx.x & 63;
    int k = lane & 15;
    int sub = lane >> 4;                               // 4 edge slots
    float acc = (sub == 0) ? g1[(size_t)node * HDIM + k] : 0.f;   // self-loop seed
    unsigned start = ptr[node];
    unsigned d = deg[node];
    for (unsigned idx = sub; idx < d; idx += 4) {
        unsigned s = csr[start + idx];
        acc += g1[(size_t)s * HDIM + k];
    }
    acc += __shfl_xor(acc, 16, 64);
    acc += __shfl_xor(acc, 32, 64);
    if (lane < 16) agg1[(size_t)node * HDIM + lane] = acc * dinv[node];
}

// ---------------------------------------------------- layer2: relu + GEMM2 ----
// v = relu(agg1 + b1); g2[i][c] = (v @ W2)[c] * dinv[i]   (stride 8, col7 = 0)
__global__ __launch_bounds__(256) void k_layer2(const float* __restrict__ agg1,
                                                const float* __restrict__ b1,
                                                const float* __restrict__ W2,
                                                const float* __restrict__ dinv,
                                                float* __restrict__ g2, int n) {
    int i = blockIdx.x * 256 + threadIdx.x;
    if (i >= n) return;
    float v[HDIM];
    const float4* a4 = (const float4*)(agg1 + (size_t)i * HDIM);
#pragma unroll
    for (int k4 = 0; k4 < 4; ++k4) {
        float4 t = a4[k4];
        v[k4 * 4 + 0] = fmaxf(t.x + b1[k4 * 4 + 0], 0.f);
        v[k4 * 4 + 1] = fmaxf(t.y + b1[k4 * 4 + 1], 0.f);
        v[k4 * 4 + 2] = fmaxf(t.z + b1[k4 * 4 + 2], 0.f);
        v[k4 * 4 + 3] = fmaxf(t.w + b1[k4 * 4 + 3], 0.f);
    }
    float di = dinv[i];
#pragma unroll
    for (int c = 0; c < CDIM; ++c) {
        float h = 0.f;
#pragma unroll
        for (int k = 0; k < HDIM; ++k) h += v[k] * W2[(size_t)k * CDIM + c];
        g2[(size_t)i * 8 + c] = h * di;
    }
    g2[(size_t)i * 8 + 7] = 0.f;
}

// -------------------------------------------------- gather 2 (wave/node) ----
__global__ __launch_bounds__(256) void k_gather2(const unsigned* __restrict__ ptr,
                                                 const unsigned* __restrict__ deg,
                                                 const unsigned* __restrict__ csr,
                                                 const float* __restrict__ g2,
                                                 const float* __restrict__ dinv,
                                                 float* __restrict__ agg2, int n) {
    int node = blockIdx.x * 4 + (threadIdx.x >> 6);
    if (node >= n) return;
    int lane = threadIdx.x & 63;
    int k = lane & 7;
    int sub = lane >> 3;                               // 8 edge slots
    float acc = (sub == 0) ? g2[(size_t)node * 8 + k] : 0.f;
    unsigned start = ptr[node];
    unsigned d = deg[node];
    for (unsigned idx = sub; idx < d; idx += 8) {
        unsigned s = csr[start + idx];
        acc += g2[(size_t)s * 8 + k];
    }
    acc += __shfl_xor(acc, 8, 64);
    acc += __shfl_xor(acc, 16, 64);
    acc += __shfl_xor(acc, 32, 64);
    if (lane < 8) agg2[(size_t)node * 8 + lane] = acc * dinv[node];
}

// ------------------------------------------------------- bias + logsoftmax ----
__global__ __launch_bounds__(256) void k_out(const float* __restrict__ agg2,
                                             const float* __restrict__ b2,
                                             float* __restrict__ out, int n) {
    int i = blockIdx.x * 256 + threadIdx.x;
    if (i >= n) return;
    float z[CDIM];
    float m = -1e30f;
#pragma unroll
    for (int c = 0; c < CDIM; ++c) {
        z[c] = agg2[(size_t)i * 8 + c] + b2[c];
        m = fmaxf(m, z[c]);
    }
    float s = 0.f;
#pragma unroll
    for (int c = 0; c < CDIM; ++c) s += expf(z[c] - m);
    float l = logf(s);
#pragma unroll
    for (int c = 0; c < CDIM; ++c) out[(size_t)i * CDIM + c] = z[c] - m - l;
}

// ---------------------------------------------------------------- launcher ----
static inline size_t align4w(size_t w) { return (w + 3) & ~(size_t)3; }

extern "C" void kernel_launch(void* const* d_in, const int* in_sizes, int n_in,
                              void* d_out, int out_size, void* d_ws, size_t ws_size,
                              hipStream_t stream) {
    const float* x  = (const float*)d_in[0];
    const int*   ei = (const int*)d_in[1];
    const float* W1 = (const float*)d_in[2];
    const float* b1 = (const float*)d_in[3];
    const float* W2 = (const float*)d_in[4];
    const float* b2 = (const float*)d_in[5];
    float* out = (float*)d_out;

    int n = in_sizes[0] / F_IN;
    int E = in_sizes[1] / 2;
    const int* src = ei;
    const int* dst = ei + E;

    int nb = (n + 255) / 256;          // node blocks (also #scan blocks)
    int eb = (E + 255) / 256;          // edge blocks
    int gb = (n + 3) / 4;              // gather blocks (4 waves of 64 = 1 node/wave)

    // workspace layout (32-bit words, each region 16B-aligned)
    unsigned* w = (unsigned*)d_ws;
    size_t o = 0;
    float*    dinv = (float*)(w + o);    o += align4w((size_t)n);
    unsigned* deg  = w + o;              o += align4w((size_t)n);
    unsigned* ptr  = w + o;              o += align4w((size_t)n);
    unsigned* fill = w + o;              o += align4w((size_t)n);
    unsigned* csr  = w + o;              o += align4w((size_t)E);
    float*    g1   = (float*)(w + o);    o += align4w((size_t)n * HDIM);
    float*    agg1 = (float*)(w + o);    o += align4w((size_t)n * HDIM);
    float*    g2   = (float*)(w + o);    o += align4w((size_t)n * 8);
    float*    agg2 = (float*)(w + o);    o += align4w((size_t)n * 8);
    unsigned* bsum = w + o;              o += align4w((size_t)nb);

    hipLaunchKernelGGL(k_zero,       dim3(nb), dim3(256), 0, stream, deg, n);
    hipLaunchKernelGGL(k_hist,       dim3(eb), dim3(256), 0, stream, dst, deg, E);
    hipLaunchKernelGGL(k_scan_block, dim3(nb), dim3(256), 0, stream, deg, ptr, bsum, n);
    hipLaunchKernelGGL(k_scan_sums,  dim3(1),  dim3(512), 0, stream, bsum, nb);
    hipLaunchKernelGGL(k_scan_add,   dim3(nb), dim3(256), 0, stream, ptr, fill, bsum, deg, dinv, n);
    hipLaunchKernelGGL(k_csr,        dim3(eb), dim3(256), 0, stream, src, dst, fill, csr, E);
    hipLaunchKernelGGL(k_gemm1,      dim3(nb), dim3(256), 0, stream, x, W1, dinv, g1, n);
    hipLaunchKernelGGL(k_gather1,    dim3(gb), dim3(256), 0, stream, ptr, deg, csr, g1, dinv, agg1, n);
    hipLaunchKernelGGL(k_layer2,     dim3(nb), dim3(256), 0, stream, agg1, b1, W2, dinv, g2, n);
    hipLaunchKernelGGL(k_gather2,    dim3(gb), dim3(256), 0, stream, ptr, deg, csr, g2, dinv, agg2, n);
    hipLaunchKernelGGL(k_out,        dim3(nb), dim3(256), 0, stream, agg2, b2, out, n);
}

// Round 4
// 560.131 us; speedup vs baseline: 1.5587x; 1.5587x over previous
//
#include <hip/hip_runtime.h>
#include <math.h>

#define F_IN 512
#define HDIM 16
#define CDIM 7
#define NBLK 1024          // partition blocks for p2a/p2b
#define BSH  9             // 512 nodes per bucket
#define BMASK ((1u << BSH) - 1u)

// ---------------------------------------------- pass 2a: coarse histogram ----
// hist_g[bucket][blk] = #edges of this block with dst in bucket
__global__ __launch_bounds__(256) void k_p2a(const int* __restrict__ dst,
                                             unsigned* __restrict__ hist_g,
                                             int E, int nbuck) {
    __shared__ unsigned lh[256];
    int blk = blockIdx.x;
    int t = threadIdx.x;
    lh[t] = 0u;
    __syncthreads();
    int per = (E + NBLK - 1) / NBLK;
    int s0 = blk * per;
    int e0 = min(E, s0 + per);
    for (int i = s0 + t; i < e0; i += 256)
        atomicAdd(&lh[((unsigned)dst[i]) >> BSH], 1u);
    __syncthreads();
    if (t < nbuck) hist_g[(size_t)t * NBLK + blk] = lh[t];
}

// ------------------------- scan within each bucket over the 1024 blocks ----
// hist_g row -> exclusive bases (in place); count[b] = bucket total
__global__ __launch_bounds__(256) void k_scan_buckets(unsigned* __restrict__ hist_g,
                                                      unsigned* __restrict__ count) {
    __shared__ unsigned s[256];
    int b = blockIdx.x;
    int t = threadIdx.x;
    unsigned* row = hist_g + (size_t)b * NBLK;
    unsigned h[4];
#pragma unroll
    for (int j = 0; j < 4; ++j) h[j] = row[4 * t + j];
    unsigned p = h[0] + h[1] + h[2] + h[3];
    s[t] = p;
    __syncthreads();
    for (int off = 1; off < 256; off <<= 1) {
        unsigned u = (t >= off) ? s[t - off] : 0u;
        __syncthreads();
        s[t] += u;
        __syncthreads();
    }
    unsigned run = s[t] - p;   // exclusive across threads
#pragma unroll
    for (int j = 0; j < 4; ++j) { unsigned hh = h[j]; row[4 * t + j] = run; run += hh; }
    if (t == 255) count[b] = run;
}

// ------------------------------------ exclusive scan of bucket totals ----
__global__ __launch_bounds__(256) void k_scan_tot(const unsigned* __restrict__ count,
                                                  unsigned* __restrict__ boff, int nbuck) {
    __shared__ unsigned s[256];
    int t = threadIdx.x;
    unsigned v = (t < nbuck) ? count[t] : 0u;
    s[t] = v;
    __syncthreads();
    for (int off = 1; off < 256; off <<= 1) {
        unsigned u = (t >= off) ? s[t - off] : 0u;
        __syncthreads();
        s[t] += u;
        __syncthreads();
    }
    if (t < nbuck) boff[t] = s[t] - v;
}

// --------------------- pass 2b: scatter packed pairs into bucket regions ----
__global__ __launch_bounds__(256) void k_p2b(const int* __restrict__ src,
                                             const int* __restrict__ dst,
                                             const unsigned* __restrict__ hist_g, // bases now
                                             const unsigned* __restrict__ boff,
                                             unsigned* __restrict__ pairs,
                                             int E, int nbuck) {
    __shared__ unsigned basel[256];
    __shared__ unsigned cnt[256];
    int blk = blockIdx.x;
    int t = threadIdx.x;
    if (t < nbuck) basel[t] = hist_g[(size_t)t * NBLK + blk] + boff[t];
    cnt[t] = 0u;
    __syncthreads();
    int per = (E + NBLK - 1) / NBLK;
    int s0 = blk * per;
    int e0 = min(E, s0 + per);
    for (int i = s0 + t; i < e0; i += 256) {
        unsigned ss = (unsigned)src[i];
        unsigned dd = (unsigned)dst[i];
        unsigned b = dd >> BSH;
        unsigned r = atomicAdd(&cnt[b], 1u);
        pairs[basel[b] + r] = (ss << BSH) | (dd & BMASK);
    }
}

// ----------------- pass 3: per-bucket local counting sort -> CSR + dinv ----
__global__ __launch_bounds__(1024) void k_p3(const unsigned* __restrict__ pairs,
                                             const unsigned* __restrict__ boff,
                                             const unsigned* __restrict__ count,
                                             unsigned* __restrict__ csr,
                                             unsigned* __restrict__ ptr_g,
                                             unsigned* __restrict__ deg_g,
                                             float* __restrict__ dinv, int n) {
    __shared__ unsigned hist[512];
    __shared__ unsigned cur[512];
    __shared__ unsigned sc[256];
    int b = blockIdx.x;
    int t = threadIdx.x;
    unsigned start = boff[b];
    unsigned cnt = count[b];
    if (t < 512) hist[t] = 0u;
    __syncthreads();
    for (unsigned i = t; i < cnt; i += 1024)
        atomicAdd(&hist[pairs[start + i] & BMASK], 1u);
    __syncthreads();
    unsigned h0 = 0, h1 = 0, part = 0;
    if (t < 256) { h0 = hist[2 * t]; h1 = hist[2 * t + 1]; part = h0 + h1; sc[t] = part; }
    __syncthreads();
    for (int off = 1; off < 256; off <<= 1) {
        unsigned u = 0;
        if (t < 256 && t >= off) u = sc[t - off];
        __syncthreads();
        if (t < 256) sc[t] += u;
        __syncthreads();
    }
    if (t < 256) {
        unsigned x = sc[t] - part;        // exclusive
        cur[2 * t] = x;
        cur[2 * t + 1] = x + h0;
        int base_node = b << BSH;
#pragma unroll
        for (int j = 0; j < 2; ++j) {
            int l = 2 * t + j;
            int node = base_node + l;
            if (node < n) {
                unsigned hv = (j == 0) ? h0 : h1;
                ptr_g[node] = start + cur[l];
                deg_g[node] = hv;
                dinv[node] = rsqrtf((float)hv + 1.0f);   // +1 self-loop
            }
        }
    }
    __syncthreads();
    for (unsigned i = t; i < cnt; i += 1024) {
        unsigned pv = pairs[start + i];
        unsigned slot = atomicAdd(&cur[pv & BMASK], 1u);
        csr[start + slot] = pv >> BSH;
    }
}

// ------------------------------------------------------------------ GEMM1 ----
// g1[row][k] = (x[row] @ W1)[k] * dinv[row]
__global__ __launch_bounds__(256) void k_gemm1(const float* __restrict__ x,
                                               const float* __restrict__ W,
                                               const float* __restrict__ dinv,
                                               float* __restrict__ g1, int n) {
    int row = blockIdx.x * 256 + threadIdx.x;
    if (row >= n) return;
    const float4* __restrict__ x4 = (const float4*)(x + (size_t)row * F_IN);
    float acc[HDIM];
#pragma unroll
    for (int k = 0; k < HDIM; ++k) acc[k] = 0.f;
#pragma unroll 2
    for (int f4 = 0; f4 < F_IN / 4; ++f4) {
        float4 xv = x4[f4];
#pragma unroll
        for (int j = 0; j < 4; ++j) {
            float xs = (&xv.x)[j];
            const float* wrow = W + (size_t)(f4 * 4 + j) * HDIM;  // wave-uniform -> scalar
#pragma unroll
            for (int k = 0; k < HDIM; ++k) acc[k] += xs * wrow[k];
        }
    }
    float di = dinv[row];
    float4* g1o = (float4*)(g1 + (size_t)row * HDIM);
#pragma unroll
    for (int k4 = 0; k4 < 4; ++k4) {
        float4 g;
        g.x = acc[k4 * 4 + 0] * di;
        g.y = acc[k4 * 4 + 1] * di;
        g.z = acc[k4 * 4 + 2] * di;
        g.w = acc[k4 * 4 + 3] * di;
        g1o[k4] = g;
    }
}

// -------------------------------------------------- gather 1 (wave/node) ----
__global__ __launch_bounds__(256) void k_gather1(const unsigned* __restrict__ ptr,
                                                 const unsigned* __restrict__ deg,
                                                 const unsigned* __restrict__ csr,
                                                 const float* __restrict__ g1,
                                                 const float* __restrict__ dinv,
                                                 float* __restrict__ agg1, int n) {
    int node = blockIdx.x * 4 + (threadIdx.x >> 6);
    if (node >= n) return;
    int lane = threadIdx.x & 63;
    int k = lane & 15;
    int sub = lane >> 4;
    float acc = (sub == 0) ? g1[(size_t)node * HDIM + k] : 0.f;   // self-loop seed
    unsigned start = ptr[node];
    unsigned d = deg[node];
    for (unsigned i = sub; i < d; i += 4)
        acc += g1[(size_t)csr[start + i] * HDIM + k];
    acc += __shfl_xor(acc, 16, 64);
    acc += __shfl_xor(acc, 32, 64);
    if (lane < 16) agg1[(size_t)node * HDIM + lane] = acc * dinv[node];
}

// ---------------------------------------------------- layer2: relu + GEMM2 ----
__global__ __launch_bounds__(256) void k_layer2(const float* __restrict__ agg1,
                                                const float* __restrict__ b1,
                                                const float* __restrict__ W2,
                                                const float* __restrict__ dinv,
                                                float* __restrict__ g2, int n) {
    int i = blockIdx.x * 256 + threadIdx.x;
    if (i >= n) return;
    float v[HDIM];
    const float4* a4 = (const float4*)(agg1 + (size_t)i * HDIM);
#pragma unroll
    for (int k4 = 0; k4 < 4; ++k4) {
        float4 t = a4[k4];
        v[k4 * 4 + 0] = fmaxf(t.x + b1[k4 * 4 + 0], 0.f);
        v[k4 * 4 + 1] = fmaxf(t.y + b1[k4 * 4 + 1], 0.f);
        v[k4 * 4 + 2] = fmaxf(t.z + b1[k4 * 4 + 2], 0.f);
        v[k4 * 4 + 3] = fmaxf(t.w + b1[k4 * 4 + 3], 0.f);
    }
    float di = dinv[i];
#pragma unroll
    for (int c = 0; c < CDIM; ++c) {
        float h = 0.f;
#pragma unroll
        for (int k = 0; k < HDIM; ++k) h += v[k] * W2[(size_t)k * CDIM + c];
        g2[(size_t)i * 8 + c] = h * di;
    }
    g2[(size_t)i * 8 + 7] = 0.f;   // must be 0: gather2 lane k=7 reads it
}

// ------------------------- gather 2 + bias + logsoftmax (fused, wave/node) ----
__global__ __launch_bounds__(256) void k_gather2_out(const unsigned* __restrict__ ptr,
                                                     const unsigned* __restrict__ deg,
                                                     const unsigned* __restrict__ csr,
                                                     const float* __restrict__ g2,
                                                     const float* __restrict__ dinv,
                                                     const float* __restrict__ b2,
                                                     float* __restrict__ out, int n) {
    int node = blockIdx.x * 4 + (threadIdx.x >> 6);
    if (node >= n) return;
    int lane = threadIdx.x & 63;
    int k = lane & 7;
    int sub = lane >> 3;
    float acc = (sub == 0) ? g2[(size_t)node * 8 + k] : 0.f;
    unsigned start = ptr[node];
    unsigned d = deg[node];
    for (unsigned i = sub; i < d; i += 8)
        acc += g2[(size_t)csr[start + i] * 8 + k];
    acc += __shfl_xor(acc, 8, 64);
    acc += __shfl_xor(acc, 16, 64);
    acc += __shfl_xor(acc, 32, 64);
    // every lane now holds the class-k sum; 8-lane groups are replicas
    float z = (k < CDIM) ? acc * dinv[node] + b2[k] : -1e30f;
    float m = z;
    m = fmaxf(m, __shfl_xor(m, 1, 64));
    m = fmaxf(m, __shfl_xor(m, 2, 64));
    m = fmaxf(m, __shfl_xor(m, 4, 64));
    float ex = (k < CDIM) ? expf(z - m) : 0.f;
    float ssum = ex;
    ssum += __shfl_xor(ssum, 1, 64);
    ssum += __shfl_xor(ssum, 2, 64);
    ssum += __shfl_xor(ssum, 4, 64);
    if (lane < CDIM) out[(size_t)node * CDIM + lane] = z - m - logf(ssum);
}

// ---------------------------------------------------------------- launcher ----
static inline size_t align4w(size_t w) { return (w + 3) & ~(size_t)3; }

extern "C" void kernel_launch(void* const* d_in, const int* in_sizes, int n_in,
                              void* d_out, int out_size, void* d_ws, size_t ws_size,
                              hipStream_t stream) {
    const float* x  = (const float*)d_in[0];
    const int*   ei = (const int*)d_in[1];
    const float* W1 = (const float*)d_in[2];
    const float* b1 = (const float*)d_in[3];
    const float* W2 = (const float*)d_in[4];
    const float* b2 = (const float*)d_in[5];
    float* out = (float*)d_out;

    int n = in_sizes[0] / F_IN;
    int E = in_sizes[1] / 2;
    const int* src = ei;
    const int* dst = ei + E;
    int nbuck = (n + (1 << BSH) - 1) >> BSH;   // 196 for n=100000 (<=256 required)

    int nb = (n + 255) / 256;
    int gb = (n + 3) / 4;

    // workspace layout (32-bit words, 16B-aligned regions)
    unsigned* w = (unsigned*)d_ws;
    size_t o = 0;
    unsigned* hist_g = w + o;             o += align4w((size_t)nbuck * NBLK);
    unsigned* count  = w + o;             o += align4w((size_t)nbuck);
    unsigned* boff   = w + o;             o += align4w((size_t)nbuck);
    unsigned* pairs  = w + o;             o += align4w((size_t)E);
    unsigned* csr    = w + o;             o += align4w((size_t)E);
    unsigned* ptr    = w + o;             o += align4w((size_t)n);
    unsigned* deg    = w + o;             o += align4w((size_t)n);
    float*    dinv   = (float*)(w + o);   o += align4w((size_t)n);
    float*    g1     = (float*)(w + o);   o += align4w((size_t)n * HDIM);
    float*    agg1   = (float*)(w + o);   o += align4w((size_t)n * HDIM);
    float*    g2     = (float*)(w + o);   o += align4w((size_t)n * 8);

    hipLaunchKernelGGL(k_p2a,          dim3(NBLK),  dim3(256),  0, stream, dst, hist_g, E, nbuck);
    hipLaunchKernelGGL(k_scan_buckets, dim3(nbuck), dim3(256),  0, stream, hist_g, count);
    hipLaunchKernelGGL(k_scan_tot,     dim3(1),     dim3(256),  0, stream, count, boff, nbuck);
    hipLaunchKernelGGL(k_p2b,          dim3(NBLK),  dim3(256),  0, stream, src, dst, hist_g, boff, pairs, E, nbuck);
    hipLaunchKernelGGL(k_p3,           dim3(nbuck), dim3(1024), 0, stream, pairs, boff, count, csr, ptr, deg, dinv, n);
    hipLaunchKernelGGL(k_gemm1,        dim3(nb),    dim3(256),  0, stream, x, W1, dinv, g1, n);
    hipLaunchKernelGGL(k_gather1,      dim3(gb),    dim3(256),  0, stream, ptr, deg, csr, g1, dinv, agg1, n);
    hipLaunchKernelGGL(k_layer2,       dim3(nb),    dim3(256),  0, stream, agg1, b1, W2, dinv, g2, n);
    hipLaunchKernelGGL(k_gather2_out,  dim3(gb),    dim3(256),  0, stream, ptr, deg, csr, g2, dinv, b2, out, n);
}